// Round 2
// baseline (602.436 us; speedup 1.0000x reference)
//
#include <hip/hip_runtime.h>
#include <stdint.h>

#define NFFT  1024
#define MROWS 32768
#define GRID  2048          // 4 waves/block -> 8192 waves -> 4 rows per wave

// complex-index pad: +1 complex per 16 -> stride-16/64/256 exchange patterns
// land <=2-way (free) on the 32 LDS banks; max Pc(1023)=1086 -> 1088 slots.
__device__ __forceinline__ int Pc(int i) { return i + (i >> 4); }

// in-place complex DFT4 (forward, e^{-2pi i kr/4}); legs (a,b,c,d) -> outputs k=0..3
__device__ __forceinline__ void dft4(float& ar, float& ai, float& br_, float& bi_,
                                     float& cr, float& ci, float& dr, float& di) {
  const float t0r = ar + cr,  t0i = ai + ci;
  const float t1r = ar - cr,  t1i = ai - ci;
  const float t2r = br_ + dr, t2i = bi_ + di;
  const float t3r = bi_ - di, t3i = dr - br_;   // -i*(b-d)
  ar  = t0r + t2r; ai  = t0i + t2i;
  br_ = t1r + t3r; bi_ = t1i + t3i;
  cr  = t0r - t2r; ci  = t0i - t2i;
  dr  = t1r - t3r; di  = t1i - t3i;
}

__device__ __forceinline__ void cmul(float& xr, float& xi, float c, float s) {
  const float r = xr * c - xi * s;
  xi = xr * s + xi * c;
  xr = r;
}

// Batched 1024-pt complex forward FFT. One WAVE per row, 16 complex/thread,
// radix-4 x5 grouped [s0 s1 | X | s2 s3 | X | s4]. Private per-wave LDS buffer,
// zero __syncthreads. Twiddles = w[1][n] (exactly the reference's f64->f32
// table), all loop-invariant -> loaded once into registers.
__global__ void __launch_bounds__(256, 3)
fft1024(const float* __restrict__ xr, const float* __restrict__ xi,
        const float* __restrict__ wr, const float* __restrict__ wi,
        const float* __restrict__ br, const float* __restrict__ bi,
        float* __restrict__ out) {
  __shared__ float lds[4 * 2176];          // 4 waves x 1088 complex = 34816 B
  const int tid = threadIdx.x;
  const int w   = tid >> 6;
  const int t   = tid & 63;
  float* buf = lds + w * 2176;
  const int b = t & 15;                    // t = 16a + b
  const int a = t >> 4;

  const float* tgr = wr + NFFT;            // row 1: cos(-2pi n/1024)
  const float* tgi = wi + NFFT;            // row 1: sin(-2pi n/1024)

  // ---- loop-invariant twiddles (depend on lane only) ----
  // stage 1: W^(64*q*m), qm in {1,2,3,4,6,9} (lane-uniform)
  float T1r[10], T1i[10];
#pragma unroll
  for (int z = 0; z < 10; ++z) { T1r[z] = 1.f; T1i[z] = 0.f; }
  {
    const int zs[6] = {1, 2, 3, 4, 6, 9};
#pragma unroll
    for (int u = 0; u < 6; ++u) {
      T1r[zs[u]] = tgr[64 * zs[u]];
      T1i[zs[u]] = tgi[64 * zs[u]];
    }
  }
  // stage 2: W^(16*r*b)
  float T2r[4], T2i[4];
#pragma unroll
  for (int r = 1; r < 4; ++r) { T2r[r] = tgr[16 * r * b]; T2i[r] = tgi[16 * r * b]; }
  // stage 3: W^(4*q*(b+16*k2))
  float T3r[4][4], T3i[4][4];
#pragma unroll
  for (int q = 1; q < 4; ++q)
#pragma unroll
    for (int k = 0; k < 4; ++k) {
      const int e = 4 * q * (b + 16 * k);
      T3r[q][k] = tgr[e]; T3i[q][k] = tgi[e];
    }
  // stage 4: W^(r4*(4t+m))
  float T4r[4][4], T4i[4][4];
#pragma unroll
  for (int m = 0; m < 4; ++m)
#pragma unroll
    for (int r = 1; r < 4; ++r) {
      const int e = r * (4 * t + m);
      T4r[m][r] = tgr[e]; T4i[m][r] = tgi[e];
    }

  // ---- bias, folded: this lane always writes cols 4t+m+256k ----
  float badd_r[4][4], badd_i[4][4];        // [k4][m]
#pragma unroll
  for (int k = 0; k < 4; ++k) {
    const float4 fb = *(const float4*)(br + 4 * t + 256 * k);
    const float4 gb = *(const float4*)(bi + 4 * t + 256 * k);
    badd_r[k][0] = fb.x - gb.x; badd_i[k][0] = fb.x + gb.x;
    badd_r[k][1] = fb.y - gb.y; badd_i[k][1] = fb.y + gb.y;
    badd_r[k][2] = fb.z - gb.z; badd_i[k][2] = fb.z + gb.z;
    badd_r[k][3] = fb.w - gb.w; badd_i[k][3] = fb.w + gb.w;
  }

  for (int row = blockIdx.x * 4 + w; row < MROWS; row += GRID * 4) {
    const float* pr = xr + (size_t)row * NFFT;
    const float* px = xi + (size_t)row * NFFT;

    float vr[16], vi[16];
    // element e <-> global index t + 64e  (e = q + 4r)
#pragma unroll
    for (int e = 0; e < 16; ++e) { vr[e] = pr[t + 64 * e]; vi[e] = px[t + 64 * e]; }

    // ---- stage 0 (Ns=1): butterflies q over legs r: (q, q+4, q+8, q+12)
#pragma unroll
    for (int q = 0; q < 4; ++q)
      dft4(vr[q], vi[q], vr[q + 4], vi[q + 4], vr[q + 8], vi[q + 8], vr[q + 12], vi[q + 12]);

    // ---- stage 1 (Ns=4): butterflies m over legs q: v[q+4m], tw W^(64qm)
#pragma unroll
    for (int m = 0; m < 4; ++m) {
      if (m > 0) {
#pragma unroll
        for (int q = 1; q < 4; ++q)
          cmul(vr[q + 4 * m], vi[q + 4 * m], T1r[q * m], T1i[q * m]);
      }
      dft4(vr[4 * m], vi[4 * m], vr[1 + 4 * m], vi[1 + 4 * m],
           vr[2 + 4 * m], vi[2 + 4 * m], vr[3 + 4 * m], vi[3 + 4 * m]);
    }

    // ---- exchange 1: buf[16t + m + 4k1] = v[k1 + 4m]
#pragma unroll
    for (int u = 0; u < 16; ++u) {
      const int m = u & 3, k1 = u >> 2;
      *(float2*)&buf[2 * Pc(16 * t + u)] = make_float2(vr[k1 + 4 * m], vi[k1 + 4 * m]);
    }
    asm volatile("" ::: "memory");   // wave-sync: DS in-order in HW; fence compiler only

    // ---- stage 2 (Ns=16): read v[q+4r] = buf(t + 64q + 256r); tw W^(16 r b)
#pragma unroll
    for (int q = 0; q < 4; ++q)
#pragma unroll
      for (int r = 0; r < 4; ++r) {
        const float2 f = *(const float2*)&buf[2 * Pc(t + 64 * q + 256 * r)];
        vr[q + 4 * r] = f.x; vi[q + 4 * r] = f.y;
      }
#pragma unroll
    for (int q = 0; q < 4; ++q) {
#pragma unroll
      for (int r = 1; r < 4; ++r)
        cmul(vr[q + 4 * r], vi[q + 4 * r], T2r[r], T2i[r]);
      dft4(vr[q], vi[q], vr[q + 4], vi[q + 4], vr[q + 8], vi[q + 8], vr[q + 12], vi[q + 12]);
    }

    // ---- stage 3 (Ns=64): butterflies k2 over legs q: v[q+4k2], tw W^(4q(b+16k2))
#pragma unroll
    for (int k2 = 0; k2 < 4; ++k2) {
#pragma unroll
      for (int q = 1; q < 4; ++q)
        cmul(vr[q + 4 * k2], vi[q + 4 * k2], T3r[q][k2], T3i[q][k2]);
      dft4(vr[4 * k2], vi[4 * k2], vr[1 + 4 * k2], vi[1 + 4 * k2],
           vr[2 + 4 * k2], vi[2 + 4 * k2], vr[3 + 4 * k2], vi[3 + 4 * k2]);
    }

    // ---- exchange 2: buf[256a + b + 16k2 + 64k3] = v[k3 + 4k2]
#pragma unroll
    for (int k2 = 0; k2 < 4; ++k2)
#pragma unroll
      for (int k3 = 0; k3 < 4; ++k3)
        *(float2*)&buf[2 * Pc(256 * a + b + 16 * k2 + 64 * k3)] =
            make_float2(vr[k3 + 4 * k2], vi[k3 + 4 * k2]);
    asm volatile("" ::: "memory");

    // ---- stage 4 (Ns=256): read v[m+4r4] = buf(4t + m + 256 r4); tw W^(r4(4t+m))
#pragma unroll
    for (int m = 0; m < 4; ++m)
#pragma unroll
      for (int r = 0; r < 4; ++r) {
        const float2 f = *(const float2*)&buf[2 * Pc(4 * t + m + 256 * r)];
        vr[m + 4 * r] = f.x; vi[m + 4 * r] = f.y;
      }
    asm volatile("" ::: "memory");   // next row's exch-1 writes must stay below these reads
#pragma unroll
    for (int m = 0; m < 4; ++m) {
#pragma unroll
      for (int r = 1; r < 4; ++r)
        cmul(vr[m + 4 * r], vi[m + 4 * r], T4r[m][r], T4i[m][r]);
      dft4(vr[m], vi[m], vr[m + 4], vi[m + 4], vr[m + 8], vi[m + 8], vr[m + 12], vi[m + 12]);
    }

    // ---- store: out[row][4t + m + 256k] = v[m + 4k] + bias  (float4, fused)
    float* o_r = out + (size_t)row * NFFT;
    float* o_i = out + (size_t)MROWS * NFFT + (size_t)row * NFFT;
#pragma unroll
    for (int k = 0; k < 4; ++k) {
      float4 R, I;
      R.x = vr[0 + 4 * k] + badd_r[k][0]; I.x = vi[0 + 4 * k] + badd_i[k][0];
      R.y = vr[1 + 4 * k] + badd_r[k][1]; I.y = vi[1 + 4 * k] + badd_i[k][1];
      R.z = vr[2 + 4 * k] + badd_r[k][2]; I.z = vi[2 + 4 * k] + badd_i[k][2];
      R.w = vr[3 + 4 * k] + badd_r[k][3]; I.w = vi[3 + 4 * k] + badd_i[k][3];
      *(float4*)(o_r + 4 * t + 256 * k) = R;
      *(float4*)(o_i + 4 * t + 256 * k) = I;
    }
  }
}

extern "C" void kernel_launch(void* const* d_in, const int* in_sizes, int n_in,
                              void* d_out, int out_size, void* d_ws, size_t ws_size,
                              hipStream_t stream) {
  const float* xr = (const float*)d_in[0];
  const float* xi = (const float*)d_in[1];
  const float* wr = (const float*)d_in[2];
  const float* wi = (const float*)d_in[3];
  const float* br = (const float*)d_in[4];
  const float* bi = (const float*)d_in[5];
  float* out = (float*)d_out;
  (void)in_sizes; (void)n_in; (void)out_size; (void)d_ws; (void)ws_size;

  fft1024<<<GRID, 256, 0, stream>>>(xr, xi, wr, wi, br, bi, out);
}

// Round 3
// 560.846 us; speedup vs baseline: 1.0742x; 1.0742x over previous
//
#include <hip/hip_runtime.h>
#include <stdint.h>

#define NFFT  1024
#define MROWS 32768
#define GRID  2048          // 4 waves/block -> 8192 waves -> 4 rows per wave

// pad: +1 slot per 16 -> breaks stride-16/64/256 patterns on the 32 banks.
__device__ __forceinline__ int P(int i) { return i + (i >> 4); }

// in-place complex DFT4 (forward); legs (a,b,c,d) -> outputs k=0..3
__device__ __forceinline__ void dft4(float& ar, float& ai, float& br_, float& bi_,
                                     float& cr, float& ci, float& dr, float& di) {
  const float t0r = ar + cr,  t0i = ai + ci;
  const float t1r = ar - cr,  t1i = ai - ci;
  const float t2r = br_ + dr, t2i = bi_ + di;
  const float t3r = bi_ - di, t3i = dr - br_;   // -i*(b-d)
  ar  = t0r + t2r; ai  = t0i + t2i;
  br_ = t1r + t3r; bi_ = t1i + t3i;
  cr  = t0r - t2r; ci  = t0i - t2i;
  dr  = t1r - t3r; di  = t1i - t3i;
}

__device__ __forceinline__ void cmul(float& xr, float& xi, float c, float s) {
  const float r = xr * c - xi * s;
  xi = xr * s + xi * c;
  xr = r;
}

// Batched 1024-pt complex forward FFT. One WAVE per row, 16 complex/thread,
// radix-4 x5 grouped [s0 s1 | X | s2 s3 | X | s4]. Private per-wave LDS
// exchange buffer, zero per-row barriers. Twiddles = w[1][n] (the reference's
// own f64->f32 table) staged ONCE into a padded LDS table shared by the
// block; per-thread register arrays are gone (round-2's scratch-spill bug).
__global__ void __launch_bounds__(256, 3)
fft1024(const float* __restrict__ xr, const float* __restrict__ xi,
        const float* __restrict__ wr, const float* __restrict__ wi,
        const float* __restrict__ br, const float* __restrict__ bi,
        float* __restrict__ out) {
  __shared__ __align__(16) float twr[1088], twi[1088];   // P-padded twiddle table
  __shared__ __align__(16) float lds[4 * 2176];          // 4 waves x 1088 complex

  const int tid = threadIdx.x;
  const int w   = tid >> 6;
  const int t   = tid & 63;
  float* buf = lds + w * 2176;
  const int b  = t & 15;                   // t = 16a + b
  const int a  = t >> 4;
  const int t4 = t << 2;

  // ---- stage twiddle table once per block (only barrier in the kernel) ----
  {
    const float4 cr = *(const float4*)(wr + NFFT + 4 * tid);  // row 1 = W^n
    const float4 ci = *(const float4*)(wi + NFFT + 4 * tid);
    twr[P(4 * tid + 0)] = cr.x; twr[P(4 * tid + 1)] = cr.y;
    twr[P(4 * tid + 2)] = cr.z; twr[P(4 * tid + 3)] = cr.w;
    twi[P(4 * tid + 0)] = ci.x; twi[P(4 * tid + 1)] = ci.y;
    twi[P(4 * tid + 2)] = ci.z; twi[P(4 * tid + 3)] = ci.w;
  }
  __syncthreads();

  // ---- bias, folded (loop-invariant): lane writes cols 4t+m+256k ----
  float badd_r[4][4], badd_i[4][4];        // [k][m]
#pragma unroll
  for (int k = 0; k < 4; ++k) {
    const float4 fb = *(const float4*)(br + t4 + 256 * k);
    const float4 gb = *(const float4*)(bi + t4 + 256 * k);
    badd_r[k][0] = fb.x - gb.x; badd_i[k][0] = fb.x + gb.x;
    badd_r[k][1] = fb.y - gb.y; badd_i[k][1] = fb.y + gb.y;
    badd_r[k][2] = fb.z - gb.z; badd_i[k][2] = fb.z + gb.z;
    badd_r[k][3] = fb.w - gb.w; badd_i[k][3] = fb.w + gb.w;
  }

#pragma unroll 1                            // NEVER unroll: keeps live state flat
  for (int row = blockIdx.x * 4 + w; row < MROWS; row += GRID * 4) {
    const float* pr = xr + (size_t)row * NFFT;
    const float* px = xi + (size_t)row * NFFT;

    float vr[16], vi[16];                   // element e <-> n = t + 64e, e = q+4r
#pragma unroll
    for (int e = 0; e < 16; ++e) { vr[e] = pr[t + 64 * e]; vi[e] = px[t + 64 * e]; }

    // ---- stage 0 (Ns=1): legs r over (q, q+4, q+8, q+12), no twiddles
#pragma unroll
    for (int q = 0; q < 4; ++q)
      dft4(vr[q], vi[q], vr[q + 4], vi[q + 4], vr[q + 8], vi[q + 8], vr[q + 12], vi[q + 12]);

    // ---- stage 1 (Ns=4): legs q over v[q+4m], tw W^(64qm) (uniform broadcast)
#pragma unroll
    for (int m = 1; m < 4; ++m)
#pragma unroll
      for (int q = 1; q < 4; ++q)
        cmul(vr[q + 4 * m], vi[q + 4 * m], twr[P(64 * q * m)], twi[P(64 * q * m)]);
#pragma unroll
    for (int m = 0; m < 4; ++m)
      dft4(vr[4 * m], vi[4 * m], vr[1 + 4 * m], vi[1 + 4 * m],
           vr[2 + 4 * m], vi[2 + 4 * m], vr[3 + 4 * m], vi[3 + 4 * m]);

    // ---- exchange 1: buf[16t + m + 4k1] = v[k1 + 4m]
#pragma unroll
    for (int u = 0; u < 16; ++u) {
      const int m = u & 3, k1 = u >> 2;
      *(float2*)&buf[2 * P(16 * t + u)] = make_float2(vr[k1 + 4 * m], vi[k1 + 4 * m]);
    }
    asm volatile("" ::: "memory");

    // ---- stage 2 (Ns=16): v[q+4r] = buf(t + 64q + 256r); tw W^(16rb)
#pragma unroll
    for (int q = 0; q < 4; ++q)
#pragma unroll
      for (int r = 0; r < 4; ++r) {
        const float2 f = *(const float2*)&buf[2 * P(t + 64 * q + 256 * r)];
        vr[q + 4 * r] = f.x; vi[q + 4 * r] = f.y;
      }
    asm volatile("" ::: "memory");
    {
      float c2[4], s2[4];
#pragma unroll
      for (int r = 1; r < 4; ++r) { c2[r] = twr[P(16 * r * b)]; s2[r] = twi[P(16 * r * b)]; }
#pragma unroll
      for (int q = 0; q < 4; ++q) {
#pragma unroll
        for (int r = 1; r < 4; ++r)
          cmul(vr[q + 4 * r], vi[q + 4 * r], c2[r], s2[r]);
        dft4(vr[q], vi[q], vr[q + 4], vi[q + 4], vr[q + 8], vi[q + 8], vr[q + 12], vi[q + 12]);
      }
    }

    // ---- stage 3 (Ns=64): legs q over v[q+4k2], tw W^(4q(b+16k2))
#pragma unroll
    for (int k2 = 0; k2 < 4; ++k2) {
#pragma unroll
      for (int q = 1; q < 4; ++q) {
        const int e = 4 * q * (b + 16 * k2);
        cmul(vr[q + 4 * k2], vi[q + 4 * k2], twr[P(e)], twi[P(e)]);
      }
      dft4(vr[4 * k2], vi[4 * k2], vr[1 + 4 * k2], vi[1 + 4 * k2],
           vr[2 + 4 * k2], vi[2 + 4 * k2], vr[3 + 4 * k2], vi[3 + 4 * k2]);
    }

    // ---- exchange 2: buf[256a + b + 16k2 + 64k3] = v[k3 + 4k2]
#pragma unroll
    for (int k2 = 0; k2 < 4; ++k2)
#pragma unroll
      for (int k3 = 0; k3 < 4; ++k3)
        *(float2*)&buf[2 * P(256 * a + b + 16 * k2 + 64 * k3)] =
            make_float2(vr[k3 + 4 * k2], vi[k3 + 4 * k2]);
    asm volatile("" ::: "memory");

    // ---- stage 4 (Ns=256): v[m+4r] = buf(4t + m + 256r); tw W^(r(4t+m))
#pragma unroll
    for (int m = 0; m < 4; ++m)
#pragma unroll
      for (int r = 0; r < 4; ++r) {
        const float2 f = *(const float2*)&buf[2 * P(t4 + m + 256 * r)];
        vr[m + 4 * r] = f.x; vi[m + 4 * r] = f.y;
      }
    asm volatile("" ::: "memory");          // next iter's exch-1 stays below these reads
#pragma unroll
    for (int m = 0; m < 4; ++m) {
#pragma unroll
      for (int r = 1; r < 4; ++r) {
        const int e = r * (t4 + m);
        cmul(vr[m + 4 * r], vi[m + 4 * r], twr[P(e)], twi[P(e)]);
      }
      dft4(vr[m], vi[m], vr[m + 4], vi[m + 4], vr[m + 8], vi[m + 8], vr[m + 12], vi[m + 12]);
    }

    // ---- store: out[row][4t + m + 256k] = v[m + 4k] + bias (float4, fused)
    float* o_r = out + (size_t)row * NFFT;
    float* o_i = out + (size_t)MROWS * NFFT + (size_t)row * NFFT;
#pragma unroll
    for (int k = 0; k < 4; ++k) {
      float4 R, I;
      R.x = vr[0 + 4 * k] + badd_r[k][0]; I.x = vi[0 + 4 * k] + badd_i[k][0];
      R.y = vr[1 + 4 * k] + badd_r[k][1]; I.y = vi[1 + 4 * k] + badd_i[k][1];
      R.z = vr[2 + 4 * k] + badd_r[k][2]; I.z = vi[2 + 4 * k] + badd_i[k][2];
      R.w = vr[3 + 4 * k] + badd_r[k][3]; I.w = vi[3 + 4 * k] + badd_i[k][3];
      *(float4*)(o_r + t4 + 256 * k) = R;
      *(float4*)(o_i + t4 + 256 * k) = I;
    }
  }
}

extern "C" void kernel_launch(void* const* d_in, const int* in_sizes, int n_in,
                              void* d_out, int out_size, void* d_ws, size_t ws_size,
                              hipStream_t stream) {
  const float* xr = (const float*)d_in[0];
  const float* xi = (const float*)d_in[1];
  const float* wr = (const float*)d_in[2];
  const float* wi = (const float*)d_in[3];
  const float* br = (const float*)d_in[4];
  const float* bi = (const float*)d_in[5];
  float* out = (float*)d_out;
  (void)in_sizes; (void)n_in; (void)out_size; (void)d_ws; (void)ws_size;

  fft1024<<<GRID, 256, 0, stream>>>(xr, xi, wr, wi, br, bi, out);
}

// Round 4
// 492.155 us; speedup vs baseline: 1.2241x; 1.1396x over previous
//
#include <hip/hip_runtime.h>
#include <stdint.h>

#define NFFT  1024
#define MROWS 32768
#define GRID  2048          // 4 waves/block -> 8192 waves -> 4 rows per wave

// pad for the EXCHANGE buffers only: +1 slot per 16 -> all four exchange
// access patterns sit at the 4-lane/bank-pair b64 baseline (free).
__device__ __forceinline__ int P(int i) { return i + (i >> 4); }

// in-place complex DFT4 (forward); legs (a,b,c,d) -> outputs k=0..3
__device__ __forceinline__ void dft4(float& ar, float& ai, float& br_, float& bi_,
                                     float& cr, float& ci, float& dr, float& di) {
  const float t0r = ar + cr,  t0i = ai + ci;
  const float t1r = ar - cr,  t1i = ai - ci;
  const float t2r = br_ + dr, t2i = bi_ + di;
  const float t3r = bi_ - di, t3i = dr - br_;   // -i*(b-d)
  ar  = t0r + t2r; ai  = t0i + t2i;
  br_ = t1r + t3r; bi_ = t1i + t3i;
  cr  = t0r - t2r; ci  = t0i - t2i;
  dr  = t1r - t3r; di  = t1i - t3i;
}

__device__ __forceinline__ void cmul(float& xr, float& xi, float c, float s) {
  const float r = xr * c - xi * s;
  xi = xr * s + xi * c;
  xr = r;
}

// Batched 1024-pt complex forward FFT. One WAVE per row, 16 complex/thread,
// radix-4 x5 grouped [s0 s1 | X | s2 s3 | X | s4], zero per-row barriers.
// Twiddle sourcing this round: 256-entry UNPADDED LDS table (max exponent
// 255); higher legs derived by squaring (W^2e=(W^e)^2, W^3e=W^2e*W^e);
// stage-1's 6 twiddles are wave-uniform -> global scalar loads, SGPR-hoisted.
// Bias is re-read per row from L1 (frees 32 VGPRs -> no scratch).
__global__ void __launch_bounds__(256, 4)
fft1024(const float* __restrict__ xr, const float* __restrict__ xi,
        const float* __restrict__ wr, const float* __restrict__ wi,
        const float* __restrict__ br, const float* __restrict__ bi,
        float* __restrict__ out) {
  __shared__ __align__(16) float twr[256], twi[256];     // W^n, n<256 (2 KB)
  __shared__ __align__(16) float lds[4 * 2176];          // 4 waves x 1088 cplx

  const int tid = threadIdx.x;
  const int w   = tid >> 6;
  const int t   = tid & 63;
  float* buf = lds + w * 2176;
  const int b  = t & 15;                   // t = 16a + b
  const int a  = t >> 4;
  const int t4 = t << 2;

  // ---- 256-entry twiddle table, one element per thread (only barrier) ----
  twr[tid] = wr[NFFT + tid];               // row 1 of w_real = cos(-2pi n/1024)
  twi[tid] = wi[NFFT + tid];
  __syncthreads();

  // ---- stage-1 twiddles W^(64*qm), qm in {1,2,3,4,6,9}: wave-uniform ----
  const float u1r = wr[NFFT +  64], u1i = wi[NFFT +  64];
  const float u2r = wr[NFFT + 128], u2i = wi[NFFT + 128];
  const float u3r = wr[NFFT + 192], u3i = wi[NFFT + 192];
  const float u4r = wr[NFFT + 256], u4i = wi[NFFT + 256];
  const float u6r = wr[NFFT + 384], u6i = wi[NFFT + 384];
  const float u9r = wr[NFFT + 576], u9i = wi[NFFT + 576];

#pragma unroll 1                            // keep live state flat across rows
  for (int row = blockIdx.x * 4 + w; row < MROWS; row += GRID * 4) {
    const float* pr = xr + (size_t)row * NFFT;
    const float* px = xi + (size_t)row * NFFT;

    float vr[16], vi[16];                   // element e <-> n = t + 64e, e = q+4r
#pragma unroll
    for (int q = 0; q < 4; ++q)             // q-grouped so dft4 q can start early
#pragma unroll
      for (int r = 0; r < 4; ++r) {
        vr[q + 4 * r] = pr[t + 64 * (q + 4 * r)];
        vi[q + 4 * r] = px[t + 64 * (q + 4 * r)];
      }

    // ---- stage 0 (Ns=1): legs r over (q, q+4, q+8, q+12), no twiddles
#pragma unroll
    for (int q = 0; q < 4; ++q)
      dft4(vr[q], vi[q], vr[q + 4], vi[q + 4], vr[q + 8], vi[q + 8], vr[q + 12], vi[q + 12]);

    // ---- stage 1 (Ns=4): v[q+4m] *= W^(64qm)  (uniform SGPR constants)
    cmul(vr[5],  vi[5],  u1r, u1i);  cmul(vr[6],  vi[6],  u2r, u2i);
    cmul(vr[7],  vi[7],  u3r, u3i);
    cmul(vr[9],  vi[9],  u2r, u2i);  cmul(vr[10], vi[10], u4r, u4i);
    cmul(vr[11], vi[11], u6r, u6i);
    cmul(vr[13], vi[13], u3r, u3i);  cmul(vr[14], vi[14], u6r, u6i);
    cmul(vr[15], vi[15], u9r, u9i);
#pragma unroll
    for (int m = 0; m < 4; ++m)
      dft4(vr[4 * m], vi[4 * m], vr[1 + 4 * m], vi[1 + 4 * m],
           vr[2 + 4 * m], vi[2 + 4 * m], vr[3 + 4 * m], vi[3 + 4 * m]);

    // ---- exchange 1: buf[16t + u] = v[(u>>2) + 4(u&3)]
#pragma unroll
    for (int u = 0; u < 16; ++u) {
      const int m = u & 3, k1 = u >> 2;
      *(float2*)&buf[2 * P(16 * t + u)] = make_float2(vr[k1 + 4 * m], vi[k1 + 4 * m]);
    }
    asm volatile("" ::: "memory");

    // ---- stage 2 (Ns=16): v[q+4r] = buf(t + 64q + 256r); tw W^(16rb) derived
#pragma unroll
    for (int q = 0; q < 4; ++q)
#pragma unroll
      for (int r = 0; r < 4; ++r) {
        const float2 f = *(const float2*)&buf[2 * P(t + 64 * q + 256 * r)];
        vr[q + 4 * r] = f.x; vi[q + 4 * r] = f.y;
      }
    asm volatile("" ::: "memory");
    {
      const float c1 = twr[16 * b], s1 = twi[16 * b];
      const float c2 = c1 * c1 - s1 * s1, s2 = 2.f * c1 * s1;
      const float c3 = c2 * c1 - s2 * s1, s3 = c2 * s1 + s2 * c1;
#pragma unroll
      for (int q = 0; q < 4; ++q) {
        cmul(vr[q + 4],  vi[q + 4],  c1, s1);
        cmul(vr[q + 8],  vi[q + 8],  c2, s2);
        cmul(vr[q + 12], vi[q + 12], c3, s3);
        dft4(vr[q], vi[q], vr[q + 4], vi[q + 4], vr[q + 8], vi[q + 8], vr[q + 12], vi[q + 12]);
      }
    }

    // ---- stage 3 (Ns=64): v[q+4k2] *= W^(4q(b+16k2)), derived from q=1
#pragma unroll
    for (int k2 = 0; k2 < 4; ++k2) {
      const float c1 = twr[4 * (b + 16 * k2)], s1 = twi[4 * (b + 16 * k2)];
      const float c2 = c1 * c1 - s1 * s1, s2 = 2.f * c1 * s1;
      const float c3 = c2 * c1 - s2 * s1, s3 = c2 * s1 + s2 * c1;
      cmul(vr[1 + 4 * k2], vi[1 + 4 * k2], c1, s1);
      cmul(vr[2 + 4 * k2], vi[2 + 4 * k2], c2, s2);
      cmul(vr[3 + 4 * k2], vi[3 + 4 * k2], c3, s3);
      dft4(vr[4 * k2], vi[4 * k2], vr[1 + 4 * k2], vi[1 + 4 * k2],
           vr[2 + 4 * k2], vi[2 + 4 * k2], vr[3 + 4 * k2], vi[3 + 4 * k2]);
    }

    // ---- exchange 2: buf[256a + b + 16k2 + 64k3] = v[k3 + 4k2]
#pragma unroll
    for (int k2 = 0; k2 < 4; ++k2)
#pragma unroll
      for (int k3 = 0; k3 < 4; ++k3)
        *(float2*)&buf[2 * P(256 * a + b + 16 * k2 + 64 * k3)] =
            make_float2(vr[k3 + 4 * k2], vi[k3 + 4 * k2]);
    asm volatile("" ::: "memory");

    // ---- stage 4 (Ns=256): v[m+4r] = buf(4t + m + 256r); tw W^(r(4t+m))
#pragma unroll
    for (int m = 0; m < 4; ++m)
#pragma unroll
      for (int r = 0; r < 4; ++r) {
        const float2 f = *(const float2*)&buf[2 * P(t4 + m + 256 * r)];
        vr[m + 4 * r] = f.x; vi[m + 4 * r] = f.y;
      }
    asm volatile("" ::: "memory");          // next iter's exch-1 stays below
    {
      const float4 C = *(const float4*)&twr[t4];   // W^(4t+m), conflict-free b128
      const float4 S = *(const float4*)&twi[t4];
      const float cc[4] = {C.x, C.y, C.z, C.w};
      const float ss[4] = {S.x, S.y, S.z, S.w};
#pragma unroll
      for (int m = 0; m < 4; ++m) {
        const float c1 = cc[m], s1 = ss[m];
        const float c2 = c1 * c1 - s1 * s1, s2 = 2.f * c1 * s1;
        const float c3 = c2 * c1 - s2 * s1, s3 = c2 * s1 + s2 * c1;
        cmul(vr[m + 4],  vi[m + 4],  c1, s1);
        cmul(vr[m + 8],  vi[m + 8],  c2, s2);
        cmul(vr[m + 12], vi[m + 12], c3, s3);
        dft4(vr[m], vi[m], vr[m + 4], vi[m + 4], vr[m + 8], vi[m + 8], vr[m + 12], vi[m + 12]);
      }
    }

    // ---- store + bias (bias re-read per row; br/bi are 4KB L1-resident)
    float* o_r = out + (size_t)row * NFFT;
    float* o_i = out + (size_t)MROWS * NFFT + (size_t)row * NFFT;
#pragma unroll
    for (int k = 0; k < 4; ++k) {
      const float4 fb = *(const float4*)(br + t4 + 256 * k);
      const float4 gb = *(const float4*)(bi + t4 + 256 * k);
      float4 R, I;
      R.x = vr[0 + 4 * k] + fb.x - gb.x; I.x = vi[0 + 4 * k] + fb.x + gb.x;
      R.y = vr[1 + 4 * k] + fb.y - gb.y; I.y = vi[1 + 4 * k] + fb.y + gb.y;
      R.z = vr[2 + 4 * k] + fb.z - gb.z; I.z = vi[2 + 4 * k] + fb.z + gb.z;
      R.w = vr[3 + 4 * k] + fb.w - gb.w; I.w = vi[3 + 4 * k] + fb.w + gb.w;
      *(float4*)(o_r + t4 + 256 * k) = R;
      *(float4*)(o_i + t4 + 256 * k) = I;
    }
  }
}

extern "C" void kernel_launch(void* const* d_in, const int* in_sizes, int n_in,
                              void* d_out, int out_size, void* d_ws, size_t ws_size,
                              hipStream_t stream) {
  const float* xr = (const float*)d_in[0];
  const float* xi = (const float*)d_in[1];
  const float* wr = (const float*)d_in[2];
  const float* wi = (const float*)d_in[3];
  const float* br = (const float*)d_in[4];
  const float* bi = (const float*)d_in[5];
  float* out = (float*)d_out;
  (void)in_sizes; (void)n_in; (void)out_size; (void)d_ws; (void)ws_size;

  fft1024<<<GRID, 256, 0, stream>>>(xr, xi, wr, wi, br, bi, out);
}